// Round 12
// baseline (905.251 us; speedup 1.0000x reference)
//
#include <hip/hip_runtime.h>

// ---------------------------------------------------------------------------
// AttentionLayer: q=XWq+bq, k=XWk+bk, v=XWv+bv; S=qk^T (NO 1/sqrt(d) scale);
// P=softmax(S); out=PV.   B=4, L=4096, D=768, fp32 in/out.
//
// Precision: hi/lo f16 split (Markidis) for X,W in PROJECTION GEMMs; Q,K,V
// hi-only f16 in attention (absmax ~0.043, budget 0.114). P f16.
//
// R12 (R9-R11 post-mortem: allocator pins 128 VGPR regardless of
// launch_bounds/waves_per_eu; QK^T live set was ~175 -> chronic spill).
// Structural fix: 16 waves (1024 thr). Each wave owns 16 kv cols in QK^T
// (sacc[4]=16) and 48 out cols in PV (oacc[4][3]=48, was 96). Peak live
// ~110-125 <= 128 -> no spill. Bonus: 4 waves/SIMD (was 2) — cross-round
// data (R5 16.4 B/cy/CU @4w vs R4/R7 11.5-13 @2w) says stream rate scales
// with resident waves. Cost: softmax cross-wave reduce widens 8->16 slots
// (~+37 us total) — accepted.
//  - QT=64, KVBLK=256, 1 block/CU, LDS 140 KB, traffic 12.6 MB/CU total.
// ---------------------------------------------------------------------------

typedef _Float16 f16;
typedef _Float16 f16x8 __attribute__((ext_vector_type(8)));
typedef _Float16 f16x4 __attribute__((ext_vector_type(4)));
typedef float f32x4 __attribute__((ext_vector_type(4)));

#define NB 4
#define NL 4096
#define ND 768
#define NM (NB * NL)  // 16384 rows

__device__ __forceinline__ void split_f16(float v, f16& h, f16& l) {
    h = (f16)v;
    l = (f16)(v - (float)h);
}

// ---- convert hidden_states -> Xh, Xl (hi/lo f16), same [M][D] layout ------
__global__ __launch_bounds__(256) void k_convert_x(
    const float* __restrict__ x, f16* __restrict__ xh, f16* __restrict__ xl) {
    int i = blockIdx.x * 256 + threadIdx.x;       // group of 4 elems
    float4 v = ((const float4*)x)[i];
    float vv[4] = {v.x, v.y, v.z, v.w};
    f16x4 hv, lv;
    for (int j = 0; j < 4; ++j) {
        f16 h, l; split_f16(vv[j], h, l);
        hv[j] = h; lv[j] = l;
    }
    ((f16x4*)xh)[i] = hv;
    ((f16x4*)xl)[i] = lv;
}

// ---- transpose W [k][n] -> Wt [n][k] as hi/lo f16 (3 matrices, z picks) ---
__global__ __launch_bounds__(256) void k_convert_w(
    const float* __restrict__ Wq, const float* __restrict__ Wk,
    const float* __restrict__ Wv, f16* __restrict__ wth, f16* __restrict__ wtl) {
    __shared__ float tile[32][33];
    const float* W = blockIdx.z == 0 ? Wq : (blockIdx.z == 1 ? Wk : Wv);
    f16* th = wth + blockIdx.z * ND * ND;
    f16* tl = wtl + blockIdx.z * ND * ND;
    const int k0 = blockIdx.x * 32, n0 = blockIdx.y * 32;
    const int tx = threadIdx.x & 31, ty = threadIdx.x >> 5;  // ty 0..7
    for (int r = 0; r < 4; ++r)
        tile[r * 8 + ty][tx] = W[(k0 + r * 8 + ty) * ND + n0 + tx];
    __syncthreads();
    for (int r = 0; r < 4; ++r) {
        float v = tile[tx][r * 8 + ty];
        int n = n0 + r * 8 + ty, k = k0 + tx;
        f16 h, l; split_f16(v, h, l);
        th[n * ND + k] = h;
        tl[n * ND + k] = l;
    }
}

// ---- projection GEMM: C[M,N] = X[M,K] * W[K,N] + bias, hi/lo MFMA ---------
// z=0 -> Qh (hi only), z=1 -> Kh (hi only), z=2 -> Vt ([b][d][pos], hi)
// 128x128 tile, 4 waves in 2x2, each wave 64x64 = 4x4 frags of 16x16.
__global__ __launch_bounds__(256, 2) void k_proj(
    const f16* __restrict__ xh, const f16* __restrict__ xl,
    const f16* __restrict__ wth, const f16* __restrict__ wtl,
    const float* __restrict__ bq, const float* __restrict__ bk,
    const float* __restrict__ bv,
    f16* __restrict__ qh, f16* __restrict__ kh, f16* __restrict__ vt) {
    const int z = blockIdx.z;
    const f16* wh = wth + z * ND * ND;
    const f16* wl = wtl + z * ND * ND;
    const float* bias = z == 0 ? bq : (z == 1 ? bk : bv);
    const int m0 = blockIdx.x * 128, n0 = blockIdx.y * 128;

    // LDS: rows padded to 40 f16 (80B stride -> only 2-way bank aliasing=free)
    __shared__ f16 Ah[128 * 40], Al[128 * 40], Bh[128 * 40], Bl[128 * 40];

    const int t = threadIdx.x;
    const int lane = t & 63, quad = lane >> 4, l16 = lane & 15;
    const int wave = t >> 6, wm = wave >> 1, wn = wave & 1;

    f32x4 acc[4][4] = {};

    for (int kt = 0; kt < 24; ++kt) {
        const int k0 = kt * 32;
        __syncthreads();
        // stage 128x32 tiles (hi+lo of A and B) via 16B chunks
        for (int i = 0; i < 2; ++i) {
            int c = i * 256 + t;
            int row = c >> 2, kc = (c & 3) * 8;
            *(uint4*)&Ah[row * 40 + kc] = *(const uint4*)&xh[(m0 + row) * ND + k0 + kc];
            *(uint4*)&Al[row * 40 + kc] = *(const uint4*)&xl[(m0 + row) * ND + k0 + kc];
            *(uint4*)&Bh[row * 40 + kc] = *(const uint4*)&wh[(n0 + row) * ND + k0 + kc];
            *(uint4*)&Bl[row * 40 + kc] = *(const uint4*)&wl[(n0 + row) * ND + k0 + kc];
        }
        __syncthreads();
        f16x8 ah[4], al[4], bh[4], bl[4];
#pragma unroll
        for (int f = 0; f < 4; ++f) {
            int m = wm * 64 + f * 16 + l16;
            ah[f] = *(const f16x8*)&Ah[m * 40 + quad * 8];
            al[f] = *(const f16x8*)&Al[m * 40 + quad * 8];
            int n = wn * 64 + f * 16 + l16;
            bh[f] = *(const f16x8*)&Bh[n * 40 + quad * 8];
            bl[f] = *(const f16x8*)&Bl[n * 40 + quad * 8];
        }
#pragma unroll
        for (int fm = 0; fm < 4; ++fm)
#pragma unroll
            for (int fn = 0; fn < 4; ++fn) {
                f32x4 c = acc[fm][fn];
                c = __builtin_amdgcn_mfma_f32_16x16x32_f16(al[fm], bh[fn], c, 0, 0, 0);
                c = __builtin_amdgcn_mfma_f32_16x16x32_f16(ah[fm], bl[fn], c, 0, 0, 0);
                c = __builtin_amdgcn_mfma_f32_16x16x32_f16(ah[fm], bh[fn], c, 0, 0, 0);
                acc[fm][fn] = c;
            }
    }
    // epilogue: C/D layout col=lane&15, row=quad*4+reg  [verified m89/m91]
#pragma unroll
    for (int fm = 0; fm < 4; ++fm)
#pragma unroll
        for (int fn = 0; fn < 4; ++fn) {
            int col = n0 + wn * 64 + fn * 16 + l16;
            float bv_ = bias[col];
#pragma unroll
            for (int r = 0; r < 4; ++r) {
                int row = m0 + wm * 64 + fm * 16 + quad * 4 + r;
                float v = acc[fm][fn][r] + bv_;
                f16 h = (f16)v;
                if (z == 0) { qh[row * ND + col] = h; }
                else if (z == 1) { kh[row * ND + col] = h; }
                else {
                    int b = row >> 12, pos = row & 4095;
                    vt[(b * ND + col) * NL + pos] = h;  // V^T for PV b_frags
                }
            }
        }
}

// ---- flash attention: QT=64, KVBLK=256, 16 waves (1024 thr), 1 block/CU --
// QK^T: wave w computes FULL-d S[64 q][16 kv] for kv-cols [w*16, +16)
//   (24 k-steps), Q from LDS, K loaded directly in-loop. sacc[4]=16 regs.
// Softmax: (m,l) register-replicated per lane (rows fm*16+quad*4+r);
//   cross-wave comm = per-row scalar max/sum via mwT/psT[64][16 slots]
//   (single-buffered; race-free by bar2(kt) ordering).
// PV: wave w owns 48 output cols (dw=w*48), oacc[4][3]=48 regs; P via Pbuf;
//   V loaded per-ks inside the unrolled PV loop (compiler pipelines).
// Peak live ~110-125 <= the 128-VGPR allocation the backend insists on ->
//   no scratch (R10/R11: ~90 MB spill round-trips at 128-cap with 8 waves).
__global__ __launch_bounds__(1024) void k_attn(
    const f16* __restrict__ qh, const f16* __restrict__ kh,
    const f16* __restrict__ vt, float* __restrict__ out) {
    const int qt = blockIdx.x, b = blockIdx.y;
    const int q0 = qt * 64;
    const int t = threadIdx.x, w = t >> 6, lane = t & 63;
    const int quad = lane >> 4, l16 = lane & 15;
    const int dw = w * 48;    // PV output col chunk (16 waves x 48 = 768)
    const int kvw = w * 16;   // QK^T kv-col slice within 256

    __shared__ f16 Qbuf[64 * 776];    // Q staged once; stride 776 (16B pad)
    __shared__ f16 Pbuf[64 * 264];    // P tile [64][256+8]
    __shared__ float mwT[64][20];     // per-wave partial rowmax (slots 0..15)
    __shared__ float psT[64][20];     // per-wave partial rowsum (slots 0..15)

    const f16* kbase = &kh[((size_t)b * NL + kvw + l16) * ND];  // 16 rows/wave

    // stage Q[64][768] into LDS (read-only afterwards)
    for (int c = t; c < 6144; c += 1024) {
        int row = c / 96, col8 = (c % 96) * 8;
        *(uint4*)&Qbuf[row * 776 + col8] =
            *(const uint4*)&qh[(b * NL + q0 + row) * ND + col8];
    }
    // register-replicated softmax state for rows fm*16 + quad*4 + r
    float mreg[4][4], lreg[4][4];
#pragma unroll
    for (int fm = 0; fm < 4; ++fm)
#pragma unroll
        for (int r = 0; r < 4; ++r) { mreg[fm][r] = -1e30f; lreg[fm][r] = 0.f; }
    f32x4 oacc[4][3] = {};
    __syncthreads();

    for (int kt = 0; kt < 16; ++kt) {
        const int p0 = kt * 256;
        const f16* kb1 = kbase + (size_t)p0 * ND;

        // ---- S[64][16] = Q x K^T for this wave's 16 kv cols --------------
        f32x4 sacc[4] = {};
#pragma unroll
        for (int ks = 0; ks < 24; ++ks) {
            const int d = ks * 32 + quad * 8;
            const f16x8 b0 = *(const f16x8*)&kb1[d];
#pragma unroll
            for (int fm = 0; fm < 4; ++fm) {
                f16x8 aH = *(const f16x8*)&Qbuf[(fm * 16 + l16) * 776 + d];
                sacc[fm] = __builtin_amdgcn_mfma_f32_16x16x32_f16(aH, b0, sacc[fm], 0, 0, 0);
            }
        }

        // ---- per-wave partial rowmax over the 16 l16-lanes ----
#pragma unroll
        for (int fm = 0; fm < 4; ++fm)
#pragma unroll
            for (int r = 0; r < 4; ++r) {
                float v = sacc[fm][r];
#pragma unroll
                for (int off = 1; off < 16; off <<= 1) v = fmaxf(v, __shfl_xor(v, off, 64));
                if (l16 == 0) mwT[fm * 16 + quad * 4 + r][w] = v;
            }
        __syncthreads();  // bar1: mwT complete

        // ---- softmax: m_new identical across waves; P + partial sums ----
        float alpha[4][4];
#pragma unroll
        for (int fm = 0; fm < 4; ++fm)
#pragma unroll
            for (int r = 0; r < 4; ++r) {
                const int row = fm * 16 + quad * 4 + r;
                f32x4 a4 = *(const f32x4*)&mwT[row][0];
                f32x4 b4 = *(const f32x4*)&mwT[row][4];
                f32x4 c4 = *(const f32x4*)&mwT[row][8];
                f32x4 d4 = *(const f32x4*)&mwT[row][12];
                float t1 = fmaxf(fmaxf(a4[0], a4[1]), fmaxf(a4[2], a4[3]));
                float t2 = fmaxf(fmaxf(b4[0], b4[1]), fmaxf(b4[2], b4[3]));
                float t3 = fmaxf(fmaxf(c4[0], c4[1]), fmaxf(c4[2], c4[3]));
                float t4 = fmaxf(fmaxf(d4[0], d4[1]), fmaxf(d4[2], d4[3]));
                float tmax = fmaxf(fmaxf(t1, t2), fmaxf(t3, t4));
                float m_new = fmaxf(mreg[fm][r], tmax);
                alpha[fm][r] = __expf(mreg[fm][r] - m_new);
                mreg[fm][r] = m_new;
                float p = __expf(sacc[fm][r] - m_new);
                Pbuf[row * 264 + kvw + l16] = (f16)p;
#pragma unroll
                for (int off = 1; off < 16; off <<= 1) p += __shfl_xor(p, off, 64);
                if (l16 == 0) psT[row][w] = p;
            }
        __syncthreads();  // bar2: Pbuf + psT complete

        // ---- l update (local), O rescale ----
#pragma unroll
        for (int fm = 0; fm < 4; ++fm)
#pragma unroll
            for (int r = 0; r < 4; ++r) {
                const int row = fm * 16 + quad * 4 + r;
                f32x4 a4 = *(const f32x4*)&psT[row][0];
                f32x4 b4 = *(const f32x4*)&psT[row][4];
                f32x4 c4 = *(const f32x4*)&psT[row][8];
                f32x4 d4 = *(const f32x4*)&psT[row][12];
                float s1 = (a4[0] + a4[1]) + (a4[2] + a4[3]);
                float s2 = (b4[0] + b4[1]) + (b4[2] + b4[3]);
                float s3 = (c4[0] + c4[1]) + (c4[2] + c4[3]);
                float s4 = (d4[0] + d4[1]) + (d4[2] + d4[3]);
                lreg[fm][r] = alpha[fm][r] * lreg[fm][r] + ((s1 + s2) + (s3 + s4));
#pragma unroll
                for (int fn = 0; fn < 3; ++fn) oacc[fm][fn][r] *= alpha[fm][r];
            }

        // ---- PV over this wave's 48 cols (V loaded per-ks, unrolled) ----
#pragma unroll
        for (int ks = 0; ks < 8; ++ks) {
            f16x8 vb[3];
#pragma unroll
            for (int fn = 0; fn < 3; ++fn)
                vb[fn] = *(const f16x8*)&vt[(b * ND + dw + fn * 16 + l16) * NL +
                                            p0 + ks * 32 + quad * 8];
            f16x8 pa[4];
#pragma unroll
            for (int fm = 0; fm < 4; ++fm)
                pa[fm] = *(const f16x8*)&Pbuf[(fm * 16 + l16) * 264 + ks * 32 + quad * 8];
#pragma unroll
            for (int fn = 0; fn < 3; ++fn)
#pragma unroll
                for (int fm = 0; fm < 4; ++fm)
                    oacc[fm][fn] = __builtin_amdgcn_mfma_f32_16x16x32_f16(
                        pa[fm], vb[fn], oacc[fm][fn], 0, 0, 0);
        }
        // no 3rd barrier: kt+1's mwT/psT/Pbuf writes occur after bar1(kt+1)
        // (or post-QK^T), which happens-after all waves passed bar2(kt),
        // which is after all reads of kt's values. Race-free.
    }

    // ---- epilogue: out = O / l (all state in registers) ----
#pragma unroll
    for (int fm = 0; fm < 4; ++fm)
#pragma unroll
        for (int fn = 0; fn < 3; ++fn) {
            int col = dw + fn * 16 + l16;
#pragma unroll
            for (int r = 0; r < 4; ++r) {
                int row = b * NL + q0 + fm * 16 + quad * 4 + r;
                out[row * ND + col] = oacc[fm][fn][r] / lreg[fm][r];
            }
        }
}

extern "C" void kernel_launch(void* const* d_in, const int* in_sizes, int n_in,
                              void* d_out, int out_size, void* d_ws, size_t ws_size,
                              hipStream_t stream) {
    const float* hs = (const float*)d_in[0];
    const float* Wq = (const float*)d_in[1];
    const float* bq = (const float*)d_in[2];
    const float* Wk = (const float*)d_in[3];
    const float* bk = (const float*)d_in[4];
    const float* Wv = (const float*)d_in[5];
    const float* bv = (const float*)d_in[6];
    float* out = (float*)d_out;

    char* ws = (char*)d_ws;
    size_t off = 0;
    auto alloc = [&](size_t bytes) {
        void* p = ws + off;
        off += (bytes + 255) & ~(size_t)255;
        return p;
    };
    const size_t MD = (size_t)NM * ND;  // 12,582,912
    f16* Xh = (f16*)alloc(MD * 2);
    f16* Xl = (f16*)alloc(MD * 2);
    f16* Wth = (f16*)alloc((size_t)3 * ND * ND * 2);
    f16* Wtl = (f16*)alloc((size_t)3 * ND * ND * 2);
    f16* Qh = (f16*)alloc(MD * 2);
    f16* Kh = (f16*)alloc(MD * 2);
    f16* Vt = (f16*)alloc(MD * 2);
    (void)ws_size; (void)in_sizes; (void)n_in; (void)out_size;

    k_convert_x<<<dim3(MD / 1024), 256, 0, stream>>>(hs, Xh, Xl);
    k_convert_w<<<dim3(24, 24, 3), 256, 0, stream>>>(Wq, Wk, Wv, Wth, Wtl);
    k_proj<<<dim3(NM / 128, ND / 128, 3), 256, 0, stream>>>(
        Xh, Xl, Wth, Wtl, bq, bk, bv, Qh, Kh, Vt);
    k_attn<<<dim3(NL / 64, NB), 1024, 0, stream>>>(Qh, Kh, Vt, out);
}

// Round 13
// 763.436 us; speedup vs baseline: 1.1858x; 1.1858x over previous
//
#include <hip/hip_runtime.h>

// ---------------------------------------------------------------------------
// AttentionLayer: q=XWq+bq, k=XWk+bk, v=XWv+bv; S=qk^T (NO 1/sqrt(d) scale);
// P=softmax(S); out=PV.   B=4, L=4096, D=768, fp32 in/out.
//
// Precision: hi/lo f16 split (Markidis) for X,W in PROJECTION GEMMs; Q,K,V
// hi-only f16 in attention (absmax ~0.043, budget 0.114). P f16.
//
// R13 (R12 post-mortem: backend register budget = arch-VGPR half ~128 (2-
// blocks/CU heuristic, 512-thr) + AGPR half for MFMA accs. R10's arch side
// (vb48+pa16+m/l 32+addr) overflowed -> 45 MB spill; R12's 1024-thr cap 64
// was a disaster. Fix the arch side, keep the R10 config):
//  - (m,l) state -> ping-pong LDS (mstate/lstate[2][64]; read [kt&1], write
//    [kt&1^1], single writer w0/l16==0; bar2(kt)+bar1(kt+1) order the swap).
//    Frees 32 arch VGPRs. alpha computed per-lane from m_old/m_new.
//  - K load-ahead groups: QK^T = 6 unrolled groups x {8 named K loads, then
//    32 MFMAs}. In-flight/wave ~2 -> ~8 (stream was ~9-13 B/cy/CU = ~2 KB
//    in flight/CU at 200-500cy latency -> depth-limited).
//  - QT=64, KVBLK=256, 8 waves, 1 block/CU, LDS 137 KB, traffic 12.6 MB/CU.
// ---------------------------------------------------------------------------

typedef _Float16 f16;
typedef _Float16 f16x8 __attribute__((ext_vector_type(8)));
typedef _Float16 f16x4 __attribute__((ext_vector_type(4)));
typedef float f32x4 __attribute__((ext_vector_type(4)));

#define NB 4
#define NL 4096
#define ND 768
#define NM (NB * NL)  // 16384 rows

__device__ __forceinline__ void split_f16(float v, f16& h, f16& l) {
    h = (f16)v;
    l = (f16)(v - (float)h);
}

// ---- convert hidden_states -> Xh, Xl (hi/lo f16), same [M][D] layout ------
__global__ __launch_bounds__(256) void k_convert_x(
    const float* __restrict__ x, f16* __restrict__ xh, f16* __restrict__ xl) {
    int i = blockIdx.x * 256 + threadIdx.x;       // group of 4 elems
    float4 v = ((const float4*)x)[i];
    float vv[4] = {v.x, v.y, v.z, v.w};
    f16x4 hv, lv;
    for (int j = 0; j < 4; ++j) {
        f16 h, l; split_f16(vv[j], h, l);
        hv[j] = h; lv[j] = l;
    }
    ((f16x4*)xh)[i] = hv;
    ((f16x4*)xl)[i] = lv;
}

// ---- transpose W [k][n] -> Wt [n][k] as hi/lo f16 (3 matrices, z picks) ---
__global__ __launch_bounds__(256) void k_convert_w(
    const float* __restrict__ Wq, const float* __restrict__ Wk,
    const float* __restrict__ Wv, f16* __restrict__ wth, f16* __restrict__ wtl) {
    __shared__ float tile[32][33];
    const float* W = blockIdx.z == 0 ? Wq : (blockIdx.z == 1 ? Wk : Wv);
    f16* th = wth + blockIdx.z * ND * ND;
    f16* tl = wtl + blockIdx.z * ND * ND;
    const int k0 = blockIdx.x * 32, n0 = blockIdx.y * 32;
    const int tx = threadIdx.x & 31, ty = threadIdx.x >> 5;  // ty 0..7
    for (int r = 0; r < 4; ++r)
        tile[r * 8 + ty][tx] = W[(k0 + r * 8 + ty) * ND + n0 + tx];
    __syncthreads();
    for (int r = 0; r < 4; ++r) {
        float v = tile[tx][r * 8 + ty];
        int n = n0 + r * 8 + ty, k = k0 + tx;
        f16 h, l; split_f16(v, h, l);
        th[n * ND + k] = h;
        tl[n * ND + k] = l;
    }
}

// ---- projection GEMM: C[M,N] = X[M,K] * W[K,N] + bias, hi/lo MFMA ---------
// z=0 -> Qh (hi only), z=1 -> Kh (hi only), z=2 -> Vt ([b][d][pos], hi)
// 128x128 tile, 4 waves in 2x2, each wave 64x64 = 4x4 frags of 16x16.
__global__ __launch_bounds__(256, 2) void k_proj(
    const f16* __restrict__ xh, const f16* __restrict__ xl,
    const f16* __restrict__ wth, const f16* __restrict__ wtl,
    const float* __restrict__ bq, const float* __restrict__ bk,
    const float* __restrict__ bv,
    f16* __restrict__ qh, f16* __restrict__ kh, f16* __restrict__ vt) {
    const int z = blockIdx.z;
    const f16* wh = wth + z * ND * ND;
    const f16* wl = wtl + z * ND * ND;
    const float* bias = z == 0 ? bq : (z == 1 ? bk : bv);
    const int m0 = blockIdx.x * 128, n0 = blockIdx.y * 128;

    // LDS: rows padded to 40 f16 (80B stride -> only 2-way bank aliasing=free)
    __shared__ f16 Ah[128 * 40], Al[128 * 40], Bh[128 * 40], Bl[128 * 40];

    const int t = threadIdx.x;
    const int lane = t & 63, quad = lane >> 4, l16 = lane & 15;
    const int wave = t >> 6, wm = wave >> 1, wn = wave & 1;

    f32x4 acc[4][4] = {};

    for (int kt = 0; kt < 24; ++kt) {
        const int k0 = kt * 32;
        __syncthreads();
        // stage 128x32 tiles (hi+lo of A and B) via 16B chunks
        for (int i = 0; i < 2; ++i) {
            int c = i * 256 + t;
            int row = c >> 2, kc = (c & 3) * 8;
            *(uint4*)&Ah[row * 40 + kc] = *(const uint4*)&xh[(m0 + row) * ND + k0 + kc];
            *(uint4*)&Al[row * 40 + kc] = *(const uint4*)&xl[(m0 + row) * ND + k0 + kc];
            *(uint4*)&Bh[row * 40 + kc] = *(const uint4*)&wh[(n0 + row) * ND + k0 + kc];
            *(uint4*)&Bl[row * 40 + kc] = *(const uint4*)&wl[(n0 + row) * ND + k0 + kc];
        }
        __syncthreads();
        f16x8 ah[4], al[4], bh[4], bl[4];
#pragma unroll
        for (int f = 0; f < 4; ++f) {
            int m = wm * 64 + f * 16 + l16;
            ah[f] = *(const f16x8*)&Ah[m * 40 + quad * 8];
            al[f] = *(const f16x8*)&Al[m * 40 + quad * 8];
            int n = wn * 64 + f * 16 + l16;
            bh[f] = *(const f16x8*)&Bh[n * 40 + quad * 8];
            bl[f] = *(const f16x8*)&Bl[n * 40 + quad * 8];
        }
#pragma unroll
        for (int fm = 0; fm < 4; ++fm)
#pragma unroll
            for (int fn = 0; fn < 4; ++fn) {
                f32x4 c = acc[fm][fn];
                c = __builtin_amdgcn_mfma_f32_16x16x32_f16(al[fm], bh[fn], c, 0, 0, 0);
                c = __builtin_amdgcn_mfma_f32_16x16x32_f16(ah[fm], bl[fn], c, 0, 0, 0);
                c = __builtin_amdgcn_mfma_f32_16x16x32_f16(ah[fm], bh[fn], c, 0, 0, 0);
                acc[fm][fn] = c;
            }
    }
    // epilogue: C/D layout col=lane&15, row=quad*4+reg  [verified m89/m91]
#pragma unroll
    for (int fm = 0; fm < 4; ++fm)
#pragma unroll
        for (int fn = 0; fn < 4; ++fn) {
            int col = n0 + wn * 64 + fn * 16 + l16;
            float bv_ = bias[col];
#pragma unroll
            for (int r = 0; r < 4; ++r) {
                int row = m0 + wm * 64 + fm * 16 + quad * 4 + r;
                float v = acc[fm][fn][r] + bv_;
                f16 h = (f16)v;
                if (z == 0) { qh[row * ND + col] = h; }
                else if (z == 1) { kh[row * ND + col] = h; }
                else {
                    int b = row >> 12, pos = row & 4095;
                    vt[(b * ND + col) * NL + pos] = h;  // V^T for PV b_frags
                }
            }
        }
}

// ---- flash attention: QT=64, KVBLK=256, 8 waves (512 thr), 1 block/CU ----
// QK^T: wave w computes FULL-d S[64 q][32 kv] for kv-cols [w*32, +32);
//   6 unrolled groups x {8 named K loads up-front, 32 MFMAs} for in-flight
//   depth. Q from LDS.
// Softmax: (m,l) in ping-pong LDS (frees 32 arch VGPRs); alpha per-lane;
//   cross-wave comm = per-row scalar max/sum via mwT/psT.
// PV: wave w owns 96 output cols (dw=w*96); P via Pbuf; V rolling-prefetch.
__global__ __launch_bounds__(512) void k_attn(
    const f16* __restrict__ qh, const f16* __restrict__ kh,
    const f16* __restrict__ vt, float* __restrict__ out) {
    const int qt = blockIdx.x, b = blockIdx.y;
    const int q0 = qt * 64;
    const int t = threadIdx.x, w = t >> 6, lane = t & 63;
    const int quad = lane >> 4, l16 = lane & 15;
    const int dw = w * 96;    // PV output col chunk
    const int kvw = w * 32;   // QK^T kv-col slice within 256

    __shared__ f16 Qbuf[64 * 776];    // Q staged once; stride 776 (16B pad)
    __shared__ f16 Pbuf[64 * 264];    // P tile [64][256+8]
    __shared__ float mwT[64][12];     // per-wave partial rowmax (use [0..7])
    __shared__ float psT[64][12];     // per-wave partial rowsum (use [0..7])
    __shared__ float mstate[2][64];   // running max, ping-pong by kt parity
    __shared__ float lstate[2][64];   // running sum, ping-pong by kt parity

    const f16* kbase = &kh[((size_t)b * NL + kvw + l16) * ND];       // rows 0-15
    const f16* kbase2 = &kh[((size_t)b * NL + kvw + 16 + l16) * ND]; // rows 16-31

    // stage Q[64][768] into LDS (read-only afterwards)
    for (int c = t; c < 6144; c += 512) {
        int row = c / 96, col8 = (c % 96) * 8;
        *(uint4*)&Qbuf[row * 776 + col8] =
            *(const uint4*)&qh[(b * NL + q0 + row) * ND + col8];
    }
    if (t < 64) { mstate[0][t] = -1e30f; lstate[0][t] = 0.f; }
    f32x4 oacc[4][6] = {};
    __syncthreads();

    for (int kt = 0; kt < 16; ++kt) {
        const int p0 = kt * 256;
        const int cb = kt & 1;
        const f16* kb1 = kbase + (size_t)p0 * ND;
        const f16* kb2 = kbase2 + (size_t)p0 * ND;

        // ---- prefetch V ks-slice 0 (latency hides under QK^T) ----
        f16x8 vb[2][6];
#pragma unroll
        for (int fn = 0; fn < 6; ++fn)
            vb[0][fn] = *(const f16x8*)&vt[(b * ND + dw + fn * 16 + l16) * NL +
                                           p0 + quad * 8];

        // ---- S[64][32] = Q x K^T; 6 groups of 4 ks, loads batched ----
        f32x4 sacc[4][2] = {};
#pragma unroll
        for (int g = 0; g < 6; ++g) {
            f16x8 kA[4], kB[4];
#pragma unroll
            for (int i = 0; i < 4; ++i) {
                const int d = (g * 4 + i) * 32 + quad * 8;
                kA[i] = *(const f16x8*)&kb1[d];
                kB[i] = *(const f16x8*)&kb2[d];
            }
#pragma unroll
            for (int i = 0; i < 4; ++i) {
                const int d = (g * 4 + i) * 32 + quad * 8;
#pragma unroll
                for (int fm = 0; fm < 4; ++fm) {
                    f16x8 aH = *(const f16x8*)&Qbuf[(fm * 16 + l16) * 776 + d];
                    sacc[fm][0] = __builtin_amdgcn_mfma_f32_16x16x32_f16(aH, kA[i], sacc[fm][0], 0, 0, 0);
                    sacc[fm][1] = __builtin_amdgcn_mfma_f32_16x16x32_f16(aH, kB[i], sacc[fm][1], 0, 0, 0);
                }
            }
        }

        // ---- per-wave partial rowmax over 32 cols (2 fn x 16 lanes) ----
#pragma unroll
        for (int fm = 0; fm < 4; ++fm)
#pragma unroll
            for (int r = 0; r < 4; ++r) {
                float v = fmaxf(sacc[fm][0][r], sacc[fm][1][r]);
#pragma unroll
                for (int off = 1; off < 16; off <<= 1) v = fmaxf(v, __shfl_xor(v, off, 64));
                if (l16 == 0) mwT[fm * 16 + quad * 4 + r][w] = v;
            }
        __syncthreads();  // bar1: mwT complete

        // ---- softmax: m_new identical across waves; P + partial sums ----
        float alpha[4][4];
#pragma unroll
        for (int fm = 0; fm < 4; ++fm)
#pragma unroll
            for (int r = 0; r < 4; ++r) {
                const int row = fm * 16 + quad * 4 + r;
                f32x4 a4 = *(const f32x4*)&mwT[row][0];
                f32x4 b4 = *(const f32x4*)&mwT[row][4];
                float tmax = fmaxf(fmaxf(fmaxf(a4[0], a4[1]), fmaxf(a4[2], a4[3])),
                                   fmaxf(fmaxf(b4[0], b4[1]), fmaxf(b4[2], b4[3])));
                float m_old = mstate[cb][row];
                float m_new = fmaxf(m_old, tmax);
                alpha[fm][r] = __expf(m_old - m_new);
                if (w == 0 && l16 == 0) mstate[cb ^ 1][row] = m_new;
                float p0v = __expf(sacc[fm][0][r] - m_new);
                float p1v = __expf(sacc[fm][1][r] - m_new);
                Pbuf[row * 264 + kvw + l16] = (f16)p0v;
                Pbuf[row * 264 + kvw + 16 + l16] = (f16)p1v;
                float ps = p0v + p1v;
#pragma unroll
                for (int off = 1; off < 16; off <<= 1) ps += __shfl_xor(ps, off, 64);
                if (l16 == 0) psT[row][w] = ps;
            }
        __syncthreads();  // bar2: Pbuf + psT + mstate[cb^1] complete

        // ---- l update (LDS, single writer), O rescale ----
#pragma unroll
        for (int fm = 0; fm < 4; ++fm)
#pragma unroll
            for (int r = 0; r < 4; ++r) {
                const int row = fm * 16 + quad * 4 + r;
                if (w == 0 && l16 == 0) {
                    f32x4 a4 = *(const f32x4*)&psT[row][0];
                    f32x4 b4 = *(const f32x4*)&psT[row][4];
                    lstate[cb ^ 1][row] = alpha[fm][r] * lstate[cb][row] +
                                          ((a4[0] + a4[1]) + (a4[2] + a4[3])) +
                                          ((b4[0] + b4[1]) + (b4[2] + b4[3]));
                }
#pragma unroll
                for (int fn = 0; fn < 6; ++fn) oacc[fm][fn][r] *= alpha[fm][r];
            }

        // ---- PV over this wave's 96 cols, rolling V prefetch per ks ----
#pragma unroll
        for (int ks = 0; ks < 8; ++ks) {
            if (ks < 7) {
#pragma unroll
                for (int fn = 0; fn < 6; ++fn)
                    vb[(ks + 1) & 1][fn] =
                        *(const f16x8*)&vt[(b * ND + dw + fn * 16 + l16) * NL +
                                           p0 + (ks + 1) * 32 + quad * 8];
            }
            f16x8 pa[4];
#pragma unroll
            for (int fm = 0; fm < 4; ++fm)
                pa[fm] = *(const f16x8*)&Pbuf[(fm * 16 + l16) * 264 + ks * 32 + quad * 8];
#pragma unroll
            for (int fn = 0; fn < 6; ++fn)
#pragma unroll
                for (int fm = 0; fm < 4; ++fm)
                    oacc[fm][fn] = __builtin_amdgcn_mfma_f32_16x16x32_f16(
                        pa[fm], vb[ks & 1][fn], oacc[fm][fn], 0, 0, 0);
        }
        // ping-pong race-freedom: kt+1 reads mstate/lstate[cb^1]; its writes
        // go to [cb], separated from this kt's reads of [cb] by bar1/bar2.
    }

    // ---- epilogue: out = O / l (l in lstate[0] after 16 iterations) ----
    __syncthreads();
#pragma unroll
    for (int fm = 0; fm < 4; ++fm)
#pragma unroll
        for (int fn = 0; fn < 6; ++fn) {
            int col = dw + fn * 16 + l16;
#pragma unroll
            for (int r = 0; r < 4; ++r) {
                int row = b * NL + q0 + fm * 16 + quad * 4 + r;
                out[row * ND + col] =
                    oacc[fm][fn][r] / lstate[0][fm * 16 + quad * 4 + r];
            }
        }
}

extern "C" void kernel_launch(void* const* d_in, const int* in_sizes, int n_in,
                              void* d_out, int out_size, void* d_ws, size_t ws_size,
                              hipStream_t stream) {
    const float* hs = (const float*)d_in[0];
    const float* Wq = (const float*)d_in[1];
    const float* bq = (const float*)d_in[2];
    const float* Wk = (const float*)d_in[3];
    const float* bk = (const float*)d_in[4];
    const float* Wv = (const float*)d_in[5];
    const float* bv = (const float*)d_in[6];
    float* out = (float*)d_out;

    char* ws = (char*)d_ws;
    size_t off = 0;
    auto alloc = [&](size_t bytes) {
        void* p = ws + off;
        off += (bytes + 255) & ~(size_t)255;
        return p;
    };
    const size_t MD = (size_t)NM * ND;  // 12,582,912
    f16* Xh = (f16*)alloc(MD * 2);
    f16* Xl = (f16*)alloc(MD * 2);
    f16* Wth = (f16*)alloc((size_t)3 * ND * ND * 2);
    f16* Wtl = (f16*)alloc((size_t)3 * ND * ND * 2);
    f16* Qh = (f16*)alloc(MD * 2);
    f16* Kh = (f16*)alloc(MD * 2);
    f16* Vt = (f16*)alloc(MD * 2);
    (void)ws_size; (void)in_sizes; (void)n_in; (void)out_size;

    k_convert_x<<<dim3(MD / 1024), 256, 0, stream>>>(hs, Xh, Xl);
    k_convert_w<<<dim3(24, 24, 3), 256, 0, stream>>>(Wq, Wk, Wv, Wth, Wtl);
    k_proj<<<dim3(NM / 128, ND / 128, 3), 256, 0, stream>>>(
        Xh, Xl, Wth, Wtl, bq, bk, bv, Qh, Kh, Vt);
    k_attn<<<dim3(NL / 64, NB), 512, 0, stream>>>(Qh, Kh, Vt, out);
}